// Round 2
// 299.401 us; speedup vs baseline: 1.0397x; 1.0397x over previous
//
#include <hip/hip_runtime.h>
#include <math.h>

#define NB 32
#define C 256
#define H 64
#define W 64
#define HW 4096
#define KT 25  // 25 unfold tiles of 64 o-rows

// ---------------------------------------------------------------------------
// KA: three independent preps packed into one launch.
//   bid <  157 : WW[o][kk] = sum_c W10[o][c] * W8[c][kk]
//   bid == 157 : w2bar[c]  = mean_o W2[o][c]
//   bid >= 158 : t3 (relu-max per (n,c) plane), ONE WAVE PER PLANE
//                (no LDS, no barriers; 16 float4 per lane)
// ---------------------------------------------------------------------------
__global__ __launch_bounds__(256) void ka_prep(
    const float* __restrict__ x, const float* __restrict__ W2,
    const float* __restrict__ W8, const float* __restrict__ W10,
    float* __restrict__ w2bar, float* __restrict__ t3,
    float* __restrict__ WW) {
  int bid = blockIdx.x, tid = threadIdx.x;
  if (bid < 157) {
    __shared__ float s8[6400];
    for (int i = tid; i < 6400; i += 256) s8[i] = W8[i];
    __syncthreads();
    int idx = bid * 256 + tid;
    if (idx < 40000) {
      int o = idx / 25, kk = idx - o * 25;
      const float* wrow = W10 + (size_t)o * 256;
      float acc = 0.f;
#pragma unroll 8
      for (int c = 0; c < 256; ++c) acc = fmaf(wrow[c], s8[c * 25 + kk], acc);
      WW[idx] = acc;
    }
  } else if (bid == 157) {
    float s = 0.f;
#pragma unroll 8
    for (int o = 0; o < 256; ++o) s += W2[o * 256 + tid];
    w2bar[tid] = s * (1.f / 256.f);
  } else {
    // wave-per-item t3: item = (n*C+c), grid sized so item < 8192 exactly
    int item = (bid - 158) * 4 + (tid >> 6);
    int lane = tid & 63;
    const float4* xv = (const float4*)(x + (size_t)item * HW);
    float m = -3.4e38f;
#pragma unroll
    for (int i = 0; i < 16; ++i) {
      float4 v = xv[i * 64 + lane];
      m = fmaxf(m, fmaxf(fmaxf(v.x, v.y), fmaxf(v.z, v.w)));
    }
#pragma unroll
    for (int off = 32; off > 0; off >>= 1)
      m = fmaxf(m, __shfl_down(m, off, 64));
    if (lane == 0) t3[item] = fmaxf(m, 0.f);
  }
}

// ---------------------------------------------------------------------------
// KB: t5/t13 streaming pass over x; 1024 blocks (n, 32 position-chunks of
// 128), c split in half across the block -> 4 blocks/CU.
// ---------------------------------------------------------------------------
__global__ __launch_bounds__(256) void kb_t5t13(
    const float* __restrict__ x, const float* __restrict__ w2bar,
    const float* __restrict__ t3, const float* __restrict__ p4,
    const float* __restrict__ p13, float* __restrict__ t5,
    float* __restrict__ t13) {
  int bid = blockIdx.x, tid = threadIdx.x;
  int n = bid >> 5;
  int pc = bid & 31;
  int half = tid >> 7;
  int lp = tid & 127;
  int p = pc * 128 + lp;
  __shared__ float sw[256];
  __shared__ float st[256];
  __shared__ float r5[256];
  __shared__ float r9[256];
  sw[tid] = w2bar[tid];
  st[tid] = t3[n * 256 + tid];
  __syncthreads();
  const float* xp = x + (size_t)n * C * HW + (size_t)half * 128 * HW + p;
  float accs = 0.f, acc9 = 0.f;
#pragma unroll 16
  for (int c = 0; c < 128; ++c) {
    float v = xp[(size_t)c * HW];
    accs = fmaf(sw[half * 128 + c], fmaxf(v, 0.f), accs);
    acc9 = fmaf(st[half * 128 + c], v, acc9);
  }
  r5[tid] = accs;
  r9[tid] = acc9;
  __syncthreads();
  if (tid < 128) {
    int pp = pc * 128 + tid;
    float as = r5[tid] + r5[tid + 128];
    float a9 = r9[tid] + r9[tid + 128];
    t5[n * HW + pp] = p4[pp] * as;
    t13[n * HW + pp] = p13[pp] * a9;
  }
}

// ---------------------------------------------------------------------------
// KC: per (n,k) tile: stage t5 + WW rows; unfold col-max -> t7; K=25 GEMM;
// t6 + gelu; max over h -> part[n][k][w].   (proven k4, unchanged)
// ---------------------------------------------------------------------------
__global__ __launch_bounds__(256) void kc_tile(
    const float* __restrict__ t5g, const float* __restrict__ WW,
    float* __restrict__ part) {
  int n = blockIdx.x / KT;
  int k = blockIdx.x - n * KT;
  int ki = k / 5, kj = k - ki * 5;
  int tid = threadIdx.x;
  int wg = tid & 15, w0 = wg * 4;
  int rg = tid >> 4, h0 = rg * 4;
  __shared__ float s5[HW];
  __shared__ float ww[64 * 25];
  __shared__ float t7s[25 * 64];
  __shared__ float cm[5 * 64];

  const float4* t5v = (const float4*)(t5g + n * HW);
  float4* s5v = (float4*)s5;
#pragma unroll
  for (int i = 0; i < 4; ++i) s5v[i * 256 + tid] = t5v[i * 256 + tid];
  const float* wwsrc = WW + (size_t)k * 64 * 25;
  for (int i = tid; i < 1600; i += 256) ww[i] = wwsrc[i];
  __syncthreads();

  for (int idx = tid; idx < 5 * 64; idx += 256) {
    int kii = idx >> 6, wp = idx & 63;
    int lo = max(0, 3 * kii - 6), hi = min(63, 3 * kii + 57);
    float m = (kii == 2) ? -3.4e38f : 0.0f;
    for (int hp = lo; hp <= hi; ++hp) m = fmaxf(m, s5[hp * 64 + wp]);
    cm[kii * 64 + wp] = m;
  }
  __syncthreads();
  for (int idx = tid; idx < 25 * 64; idx += 256) {
    int kk = idx >> 6, w = idx & 63;
    int kki = kk / 5, kkj = kk - kki * 5;
    int wp = w + 3 * kkj - 6;
    t7s[kk * 64 + w] = (wp >= 0 && wp < 64) ? cm[kki * 64 + wp] : 0.0f;
  }
  __syncthreads();

  float4 acc[4];
#pragma unroll
  for (int j = 0; j < 4; ++j) acc[j] = make_float4(0.f, 0.f, 0.f, 0.f);
#pragma unroll
  for (int kk = 0; kk < 25; ++kk) {
    float4 tv = *(const float4*)&t7s[kk * 64 + w0];
#pragma unroll
    for (int j = 0; j < 4; ++j) {
      float a = ww[(h0 + j) * 25 + kk];
      acc[j].x = fmaf(a, tv.x, acc[j].x);
      acc[j].y = fmaf(a, tv.y, acc[j].y);
      acc[j].z = fmaf(a, tv.z, acc[j].z);
      acc[j].w = fmaf(a, tv.w, acc[j].w);
    }
  }

  int hpb = 3 * ki - 6, wpb = 3 * kj - 6;
  float pm[4] = {-3.4e38f, -3.4e38f, -3.4e38f, -3.4e38f};
#pragma unroll
  for (int j = 0; j < 4; ++j) {
    int hp = h0 + j + hpb;
    float av[4] = {acc[j].x, acc[j].y, acc[j].z, acc[j].w};
#pragma unroll
    for (int e = 0; e < 4; ++e) {
      int wp = w0 + e + wpb;
      float t6v = (hp >= 0 && hp < 64 && wp >= 0 && wp < 64)
                      ? s5[hp * 64 + wp] : 0.0f;
      float xg = av[e];
      float gl = 0.5f * xg * (1.0f + erff(xg * 0.70710678118654752f));
      pm[e] = fmaxf(pm[e], t6v + gl);
    }
  }
  __syncthreads();
  float* red = t7s;
#pragma unroll
  for (int e = 0; e < 4; ++e) red[rg * 64 + w0 + e] = pm[e];
  __syncthreads();
  if (tid < 64) {
    float m = -3.4e38f;
#pragma unroll
    for (int g = 0; g < 16; ++g) m = fmaxf(m, red[g * 64 + tid]);
    part[(n * KT + k) * 64 + tid] = m;
  }
}

// ---------------------------------------------------------------------------
// KD: t17 recomputed per block from part (cheap, removes K5 launch) + output.
// 1024 blocks: (n, cg8) each writes c = cg8*8 .. cg8*8+7.
// ---------------------------------------------------------------------------
__global__ __launch_bounds__(256) void kd_out(
    const float* __restrict__ part, const float* __restrict__ t13,
    const float* __restrict__ W18, float* __restrict__ out) {
  int bid = blockIdx.x, tid = threadIdx.x;
  int n = bid >> 5, cg8 = bid & 31;
  __shared__ float ps[1600];
  __shared__ float Mb[64];
  __shared__ float t17b[64];
  __shared__ float t13s[4096];
  const float* pp = part + (size_t)n * KT * 64;
  for (int i = tid; i < 1600; i += 256) ps[i] = pp[i];
  const float4* t13v = (const float4*)(t13 + (size_t)n * HW);
  float4* t13sv = (float4*)t13s;
#pragma unroll
  for (int i = 0; i < 4; ++i) t13sv[i * 256 + tid] = t13v[i * 256 + tid];
  __syncthreads();
  if (tid < 64) {
    float m = -3.4e38f;
#pragma unroll
    for (int t = 0; t < KT; ++t) m = fmaxf(m, ps[t * 64 + tid]);
    Mb[tid] = expf(m);
  }
  __syncthreads();
  if (tid < 64) {
    float s = 0.f;
#pragma unroll
    for (int j = 0; j < 7; ++j) {
      int wp = tid + 3 * j - 9;
      if (wp >= 0 && wp < 64) s += Mb[wp];
    }
    t17b[tid] = s * (1.0f / 7.0f);
  }
  __syncthreads();
  const float4* t17v = (const float4*)t17b;
#pragma unroll
  for (int i = 0; i < 8; ++i) {
    int c = cg8 * 8 + i;
    float4* outv = (float4*)(out + (size_t)(n * 256 + c) * HW);
#pragma unroll
    for (int it = 0; it < 4; ++it) {
      int idx = it * 256 + tid;
      int h = idx >> 4;
      int w4 = idx & 15;
      float w18 = W18[c * 64 + h];
      float4 a = t13sv[idx];
      float4 tt = t17v[w4];
      float4 o;
      o.x = a.x - w18 * tt.x;
      o.y = a.y - w18 * tt.y;
      o.z = a.z - w18 * tt.z;
      o.w = a.w - w18 * tt.w;
      outv[idx] = o;
    }
  }
}

// ---------------------------------------------------------------------------
extern "C" void kernel_launch(void* const* d_in, const int* in_sizes, int n_in,
                              void* d_out, int out_size, void* d_ws,
                              size_t ws_size, hipStream_t stream) {
  const float* x   = (const float*)d_in[0];
  const float* W2  = (const float*)d_in[1];
  const float* W8  = (const float*)d_in[2];
  const float* W10 = (const float*)d_in[3];
  const float* W18 = (const float*)d_in[4];
  const float* p4  = (const float*)d_in[5];
  const float* p13 = (const float*)d_in[6];
  float* out = (float*)d_out;

  float* ws    = (float*)d_ws;
  float* w2bar = ws;                   // 256
  float* t3    = w2bar + 256;          // 32*256
  float* t5    = t3 + NB * C;          // 32*4096
  float* t13   = t5 + NB * HW;         // 32*4096
  float* WW    = t13 + NB * HW;        // 1600*25
  float* part  = WW + 40000;           // 32*25*64

  // KA: 157 WW blocks + 1 w2bar block + 2048 t3 blocks (4 waves/block)
  ka_prep<<<dim3(158 + 2048), dim3(256), 0, stream>>>(x, W2, W8, W10, w2bar,
                                                      t3, WW);
  kb_t5t13<<<dim3(NB * 32), dim3(256), 0, stream>>>(x, w2bar, t3, p4, p13,
                                                    t5, t13);
  kc_tile<<<dim3(NB * KT), dim3(256), 0, stream>>>(t5, WW, part);
  kd_out<<<dim3(NB * 32), dim3(256), 0, stream>>>(part, t13, W18, out);
}